// Round 1
// 280.829 us; speedup vs baseline: 1.0302x; 1.0302x over previous
//
#include <hip/hip_runtime.h>
#include <cstddef>

#define NN 100000
#define DD 128
#define ND (NN * DD)
#define EE_SCAN_NB 98          // ceil(100000/1024)
#define BN_EPS 1e-5f
#define LDA 136                // LDS A row stride in bf16 elems (272 B, 16B-aligned)
#define NREP 64                // stats-accumulator replicas
#define NBKT 98                // scatter buckets: 1024 nodes each
#define EPB 4096               // edges per k_bin block

typedef __bf16 bf16_t;
typedef bf16_t bf16x8 __attribute__((ext_vector_type(8)));
typedef float f32x4 __attribute__((ext_vector_type(4)));
typedef unsigned int uint;
typedef unsigned short ushort;

// ws 4-byte-slot layout:
//   [0, ND/2)            hb   (bf16 h, [NN][128])  -- pairs/bcur alias here pre-gemm
//   [ND/2, ND)           xb   (bf16 x)
//   [ND, 3ND/2)          aggb (bf16 S*x)
//   base3 = 3ND/2:
//   [base3, +8192)       csr  (colsum replicas [64][128], zeroed)
//   [+8192, +8192)       cqr  (colsumsq replicas, zeroed)
//   [+16384, +NN)        cnt  (int, zeroed)   <- memset covers base3 .. +16384+NN
//   then: colsum[128], colsumsq[128], ptr0[NN], pcur[NN], dinv[NN],
//         bsum[136], srow[E], wb[4096 uints]

__device__ __forceinline__ ushort f2b(float f) {
    uint u = __builtin_bit_cast(uint, f);
    u += 0x7FFFu + ((u >> 16) & 1u);          // RNE
    return (ushort)(u >> 16);
}
__device__ __forceinline__ float b2f(uint s) {
    return __builtin_bit_cast(float, s << 16);
}

// int64 edge_index => high word of every entry is 0 (ids < 100000).
__device__ __forceinline__ int detect_i64(const int* __restrict__ ei) {
    __shared__ int sflag;
    int t = threadIdx.x;
    if (t < 64) {
        int hi = ei[2 * t + 1];
        unsigned long long b = __ballot(hi == 0);
        if (t == 0) sflag = (b == ~0ull) ? 1 : 0;
    }
    __syncthreads();
    return sflag;
}

// dual-role: blocks [0, nbh) histogram cols; rest pack x and W to bf16
__global__ __launch_bounds__(256) void k_prep(const int* __restrict__ ei,
                                              int* __restrict__ cnt, int E, int nbh,
                                              const float* __restrict__ x,
                                              uint* __restrict__ xb,
                                              const float* __restrict__ W,
                                              uint* __restrict__ wb) {
    if ((int)blockIdx.x < nbh) {
        int f = detect_i64(ei);
        int e = blockIdx.x * 256 + threadIdx.x;
        if (e >= E) return;
        int c = f ? ei[2 * (E + e)] : ei[E + e];
        atomicAdd(&cnt[c], 1);
        return;
    }
    int i = (blockIdx.x - nbh) * 256 + threadIdx.x;
    const float* src;
    uint* dst;
    int j;
    if (i < ND / 8) { src = x; dst = xb; j = i; }
    else { j = i - ND / 8; if (j >= (DD * DD) / 8) return; src = W; dst = wb; }
    const float4* s4 = (const float4*)src;
    float4 a = s4[2 * j], b = s4[2 * j + 1];
    uint4 o;
    o.x = (uint)f2b(a.x) | ((uint)f2b(a.y) << 16);
    o.y = (uint)f2b(a.z) | ((uint)f2b(a.w) << 16);
    o.z = (uint)f2b(b.x) | ((uint)f2b(b.y) << 16);
    o.w = (uint)f2b(b.z) | ((uint)f2b(b.w) << 16);
    ((uint4*)dst)[j] = o;
}

__global__ __launch_bounds__(256) void k_scan1(const int* __restrict__ cnt,
                                               int* __restrict__ bsum) {
    int t = threadIdx.x;
    int base = blockIdx.x * 1024 + t * 4;
    int s = 0;
#pragma unroll
    for (int i = 0; i < 4; ++i) {
        int idx = base + i;
        if (idx < NN) s += cnt[idx];
    }
    __shared__ int ls[256];
    ls[t] = s;
    __syncthreads();
    for (int o = 128; o > 0; o >>= 1) {
        if (t < o) ls[t] += ls[t + o];
        __syncthreads();
    }
    if (t == 0) bsum[blockIdx.x] = ls[0];
}

__global__ void k_scan2(int* __restrict__ bsum) {
    int t = threadIdx.x;
    __shared__ int ls[EE_SCAN_NB];
    if (t < EE_SCAN_NB) ls[t] = bsum[t];
    __syncthreads();
    if (t == 0) {
        int run = 0;
        for (int i = 0; i < EE_SCAN_NB; ++i) { int v = ls[i]; ls[i] = run; run += v; }
    }
    __syncthreads();
    if (t < EE_SCAN_NB) bsum[t] = ls[t];
}

__global__ __launch_bounds__(256) void k_scan3(const int* __restrict__ cnt,
                                               const int* __restrict__ bsum,
                                               int* __restrict__ ptr0,
                                               int* __restrict__ pcur,
                                               float* __restrict__ dinv,
                                               int* __restrict__ bcur) {
    int t = threadIdx.x;
    int base = blockIdx.x * 1024 + t * 4;
    int c[4];
    int lsum = 0;
#pragma unroll
    for (int i = 0; i < 4; ++i) {
        int idx = base + i;
        c[i] = (idx < NN) ? cnt[idx] : 0;
        lsum += c[i];
    }
    __shared__ int ls[256];
    ls[t] = lsum;
    __syncthreads();
    for (int o = 1; o < 256; o <<= 1) {
        int v = (t >= o) ? ls[t - o] : 0;
        __syncthreads();
        ls[t] += v;
        __syncthreads();
    }
    int run = ls[t] - lsum + bsum[blockIdx.x];
#pragma unroll
    for (int i = 0; i < 4; ++i) {
        int idx = base + i;
        if (idx < NN) {
            ptr0[idx] = run;
            pcur[idx] = run;
            dinv[idx] = c[i] > 0 ? rsqrtf((float)c[i]) : 0.f;
            if ((idx & 1023) == 0) bcur[idx >> 10] = run;  // bucket base = CSR start
        }
        run += c[i];
    }
}

// Phase 1 of binned scatter: partition edges into NBKT destination buckets.
// Each block histograms EPB edges in LDS, reserves one contiguous run per
// bucket with a single global atomic, then writes (row,col) pairs into its
// private runs -> every cache line of `pairs` is written by exactly one block.
__global__ __launch_bounds__(256) void k_bin(const int* __restrict__ ei,
                                             int* __restrict__ bcur,
                                             uint2* __restrict__ pairs, int E) {
    int f = detect_i64(ei);
    __shared__ int hist[NBKT], scur[NBKT];
    int t = threadIdx.x;
    if (t < NBKT) hist[t] = 0;
    __syncthreads();
    int base = blockIdx.x * EPB;
    int count = min(EPB, E - base);
    int rr[16], cc[16];
#pragma unroll
    for (int k = 0; k < 16; ++k) {
        int i = t + k * 256;
        if (i < count) {
            int e = base + i;
            int r, c;
            if (f) { r = ei[2 * e]; c = ei[2 * (E + e)]; }
            else   { r = ei[e];     c = ei[E + e]; }
            rr[k] = r; cc[k] = c;
            atomicAdd(&hist[c >> 10], 1);
        }
    }
    __syncthreads();
    if (t < NBKT) scur[t] = atomicAdd(&bcur[t], hist[t]);
    __syncthreads();
#pragma unroll
    for (int k = 0; k < 16; ++k) {
        int i = t + k * 256;
        if (i < count) {
            int b = cc[k] >> 10;
            int pos = atomicAdd(&scur[b], 1);
            pairs[pos] = (uint2){(uint)rr[k], (uint)cc[k]};
        }
    }
}

// Phase 2: pairs are bucket-grouped, so each block's srow writes land in a
// ~32KB window. Bijective XCD swizzle keeps same-bucket blocks on one XCD
// (round-robin bid%8 assumption; perf heuristic only).
__global__ __launch_bounds__(256) void k_scat2(const uint2* __restrict__ pairs,
                                               int* __restrict__ pcur,
                                               int* __restrict__ srow, int E, int nb) {
    int bid = blockIdx.x;
    int q = nb >> 3, r8 = nb & 7, xcd = bid & 7, idx = bid >> 3;
    int lb = (xcd < r8 ? xcd * (q + 1) : r8 * (q + 1) + (xcd - r8) * q) + idx;
    int base = lb * 2048 + threadIdx.x;
#pragma unroll
    for (int k = 0; k < 8; ++k) {
        int i = base + k * 256;
        if (i < E) {
            uint2 p = pairs[i];
            int pos = atomicAdd(&pcur[(int)p.y], 1);
            srow[pos] = (int)p.x;
        }
    }
}

// one wave per node. Lane l loads edge s+l's (src, dinv[src]) itself, then
// broadcast via shfl; xb row loads issued 4-deep.
__global__ __launch_bounds__(256) void k_gather(const uint* __restrict__ xb,
                                                const int* __restrict__ srow,
                                                const int* __restrict__ ptr0,
                                                const int* __restrict__ cnt,
                                                const float* __restrict__ dinv,
                                                uint* __restrict__ aggb) {
    int n = blockIdx.x * 4 + (threadIdx.x >> 6);
    int lane = threadIdx.x & 63;
    int s = ptr0[n];
    int k = cnt[n];
    float dc = dinv[n];
    float ax = 0.f, ay = 0.f;
    for (int base = 0; base < k; base += 64) {
        int m = min(k - base, 64);
        int rj = 0; float wj = 0.f;
        if (lane < m) { rj = srow[s + base + lane]; wj = dinv[rj]; }
        int j = 0;
        for (; j + 4 <= m; j += 4) {
            int r0 = __shfl(rj, j);     float w0 = __shfl(wj, j);
            int r1 = __shfl(rj, j + 1); float w1 = __shfl(wj, j + 1);
            int r2 = __shfl(rj, j + 2); float w2 = __shfl(wj, j + 2);
            int r3 = __shfl(rj, j + 3); float w3 = __shfl(wj, j + 3);
            uint v0 = xb[(size_t)r0 * 64 + lane];
            uint v1 = xb[(size_t)r1 * 64 + lane];
            uint v2 = xb[(size_t)r2 * 64 + lane];
            uint v3 = xb[(size_t)r3 * 64 + lane];
            ax = fmaf(w0, b2f(v0 & 0xFFFFu), ax); ay = fmaf(w0, b2f(v0 >> 16), ay);
            ax = fmaf(w1, b2f(v1 & 0xFFFFu), ax); ay = fmaf(w1, b2f(v1 >> 16), ay);
            ax = fmaf(w2, b2f(v2 & 0xFFFFu), ax); ay = fmaf(w2, b2f(v2 >> 16), ay);
            ax = fmaf(w3, b2f(v3 & 0xFFFFu), ax); ay = fmaf(w3, b2f(v3 >> 16), ay);
        }
        for (; j < m; ++j) {
            int r = __shfl(rj, j);
            float w = __shfl(wj, j);
            uint v = xb[(size_t)r * 64 + lane];
            ax = fmaf(w, b2f(v & 0xFFFFu), ax);
            ay = fmaf(w, b2f(v >> 16), ay);
        }
    }
    aggb[(size_t)n * 64 + lane] = (uint)f2b(dc * ax) | ((uint)f2b(dc * ay) << 16);
}

// hb = aggb @ W^T via MFMA bf16 + fused column stats into replicated banks.
__global__ __launch_bounds__(256, 2) void k_gemm(const ushort* __restrict__ aggb,
                                                 const ushort* __restrict__ wb,
                                                 ushort* __restrict__ hb,
                                                 float* __restrict__ csr,
                                                 float* __restrict__ cqr) {
    __shared__ ushort sA[64 * LDA];           // 17.4 KB
    __shared__ float cp[4][128], cq[4][128];  // 4 KB
    int t = threadIdx.x;
    int wave = t >> 6, lane = t & 63;
    int quad = lane >> 4, l16 = lane & 15;
    size_t rowbase = (size_t)blockIdx.x * 64;

    bf16x8 Bf[8][4];
#pragma unroll
    for (int ct = 0; ct < 8; ++ct)
#pragma unroll
        for (int ks = 0; ks < 4; ++ks) {
            const uint4* p =
                (const uint4*)(wb + (size_t)(ct * 16 + l16) * 128 + ks * 32 + quad * 8);
            Bf[ct][ks] = __builtin_bit_cast(bf16x8, *p);
        }

    // stage A (OOB rows -> zeros so fused stats stay exact)
#pragma unroll
    for (int i = 0; i < 4; ++i) {
        int c = t + i * 256;
        int r = c >> 4, pos = c & 15;
        size_t gr = rowbase + r;
        uint4 v = {0u, 0u, 0u, 0u};
        if (gr < NN) v = *(const uint4*)(aggb + gr * 128 + pos * 8);
        *(uint4*)(sA + r * LDA + pos * 8) = v;
    }
    __syncthreads();

    bf16x8 Af[4];
#pragma unroll
    for (int ks = 0; ks < 4; ++ks)
        Af[ks] = __builtin_bit_cast(
            bf16x8, *(const uint4*)(sA + (wave * 16 + l16) * LDA + ks * 32 + quad * 8));

    f32x4 acc[8];
#pragma unroll
    for (int ct = 0; ct < 8; ++ct) {
        acc[ct] = (f32x4){0.f, 0.f, 0.f, 0.f};
#pragma unroll
        for (int ks = 0; ks < 4; ++ks)
            acc[ct] = __builtin_amdgcn_mfma_f32_16x16x32_bf16(Af[ks], Bf[ct][ks],
                                                              acc[ct], 0, 0, 0);
    }

#pragma unroll
    for (int ct = 0; ct < 8; ++ct) {
        float ss = 0.f, qq = 0.f;
#pragma unroll
        for (int r = 0; r < 4; ++r) {
            float v = acc[ct][r];
            ss += v; qq += v * v;
            size_t row = rowbase + wave * 16 + quad * 4 + r;
            if (row < NN) hb[row * 128 + ct * 16 + l16] = f2b(v);
        }
        ss += __shfl_xor(ss, 16); ss += __shfl_xor(ss, 32);
        qq += __shfl_xor(qq, 16); qq += __shfl_xor(qq, 32);
        if (quad == 0) { cp[wave][ct * 16 + l16] = ss; cq[wave][ct * 16 + l16] = qq; }
    }
    __syncthreads();
    if (t < 128) {
        int rep = (blockIdx.x & (NREP - 1)) * 128 + t;
        atomicAdd(&csr[rep], cp[0][t] + cp[1][t] + cp[2][t] + cp[3][t]);
        atomicAdd(&cqr[rep], cq[0][t] + cq[1][t] + cq[2][t] + cq[3][t]);
    }
}

// fold the 64 replicas
__global__ void k_red(const float* __restrict__ csr, const float* __restrict__ cqr,
                      float* __restrict__ colsum, float* __restrict__ colsumsq) {
    int t = threadIdx.x;          // 256
    if (t < 128) {
        float s = 0.f;
        for (int i = 0; i < NREP; ++i) s += csr[i * 128 + t];
        colsum[t] = s;
    } else {
        int c = t - 128;
        float s = 0.f;
        for (int i = 0; i < NREP; ++i) s += cqr[i * 128 + c];
        colsumsq[c] = s;
    }
}

__global__ __launch_bounds__(256) void k_final(const uint* __restrict__ hb,
                                               const uint* __restrict__ xb,
                                               const float* __restrict__ gamma,
                                               const float* __restrict__ beta,
                                               const float* __restrict__ colsum,
                                               const float* __restrict__ colsumsq,
                                               float* __restrict__ out, int out_size) {
    int gid = blockIdx.x * 256 + threadIdx.x;     // 4-col group index over ND/4
    int c4 = (gid & 31) * 4;
    uint2 hv = ((const uint2*)hb)[gid];
    uint2 xv = ((const uint2*)xb)[gid];
    float hval[4] = { b2f(hv.x & 0xFFFFu), b2f(hv.x >> 16),
                      b2f(hv.y & 0xFFFFu), b2f(hv.y >> 16) };
    float xval[4] = { b2f(xv.x & 0xFFFFu), b2f(xv.x >> 16),
                      b2f(xv.y & 0xFFFFu), b2f(xv.y >> 16) };
    const float invN = 1.0f / NN;
    float4 o;
    float res[4];
#pragma unroll
    for (int j = 0; j < 4; ++j) {
        float m = colsum[c4 + j] * invN;
        float var = colsumsq[c4 + j] * invN - m * m;
        float inv = rsqrtf(var + BN_EPS);
        float val = (hval[j] - m) * inv * gamma[c4 + j] + beta[c4 + j];
        res[j] = fmaxf(val, 0.f) + xval[j];
    }
    o.x = res[0]; o.y = res[1]; o.z = res[2]; o.w = res[3];
    ((float4*)out)[gid] = o;
    if (gid == 0 && out_size > ND) out[ND] = 0.0f;
}

extern "C" void kernel_launch(void* const* d_in, const int* in_sizes, int n_in,
                              void* d_out, int out_size, void* d_ws, size_t ws_size,
                              hipStream_t stream) {
    const float* x     = (const float*)d_in[0];
    const int*   ei    = (const int*)d_in[1];
    const float* W     = (const float*)d_in[2];
    const float* gamma = (const float*)d_in[4];
    const float* beta  = (const float*)d_in[5];
    float* ws = (float*)d_ws;
    float* out = (float*)d_out;

    uint*   hb       = (uint*)ws;
    uint*   xb       = hb + ND / 2;
    uint*   aggb     = xb + ND / 2;
    float*  csr      = (float*)(aggb + ND / 2);        // 64*128
    float*  cqr      = csr + NREP * 128;               // 64*128
    int*    cnt      = (int*)(cqr + NREP * 128);
    float*  colsum   = (float*)(cnt + NN);
    float*  colsumsq = colsum + 128;
    int*    ptr0     = (int*)(colsumsq + 128);
    int*    pcur     = ptr0 + NN;
    float*  dinv     = (float*)(pcur + NN);
    int*    bsum     = (int*)(dinv + NN);
    int*    srow     = bsum + 136;

    int E = in_sizes[1] / 2;
    uint* wb = (uint*)(srow + E);

    // pairs + bcur alias the hb region (dead until k_gemm writes it):
    // pairs needs 2*E slots (1.6M), bcur 98 ints at slot 3M; hb region = 6.4M slots.
    uint2* pairs = (uint2*)hb;
    int*   bcur  = (int*)hb + 3000000;

    int nbh = (E + 255) / 256;
    int nbc = (ND / 8 + (DD * DD) / 8 + 255) / 256;

    // zero stat replicas + cnt
    hipMemsetAsync(csr, 0, (size_t)(2 * NREP * 128 + NN) * 4, stream);
    k_prep<<<nbh + nbc, 256, 0, stream>>>(ei, cnt, E, nbh, x, xb, W, wb);
    k_scan1<<<EE_SCAN_NB, 256, 0, stream>>>(cnt, bsum);
    k_scan2<<<1, 128, 0, stream>>>(bsum);
    k_scan3<<<EE_SCAN_NB, 256, 0, stream>>>(cnt, bsum, ptr0, pcur, dinv, bcur);
    int nbin = (E + EPB - 1) / EPB;
    k_bin<<<nbin, 256, 0, stream>>>(ei, bcur, pairs, E);
    int nsc = (E + 2047) / 2048;
    k_scat2<<<nsc, 256, 0, stream>>>(pairs, pcur, srow, E, nsc);
    k_gather<<<NN / 4, 256, 0, stream>>>(xb, srow, ptr0, cnt, dinv, aggb);
    k_gemm<<<(NN + 63) / 64, 256, 0, stream>>>((const ushort*)aggb, (const ushort*)wb,
                                               (ushort*)hb, csr, cqr);
    k_red<<<1, 256, 0, stream>>>(csr, cqr, colsum, colsumsq);
    k_final<<<ND / (256 * 4), 256, 0, stream>>>(hb, xb, gamma, beta,
                                                colsum, colsumsq, out, out_size);
}

// Round 2
// 249.365 us; speedup vs baseline: 1.1602x; 1.1262x over previous
//
#include <hip/hip_runtime.h>
#include <cstddef>

#define NN 100000
#define DD 128
#define ND (NN * DD)
#define BN_EPS 1e-5f
#define LDA 136                // LDS A row stride in bf16 elems (272 B, 16B-aligned)
#define NREP 64                // stats-accumulator replicas
#define NBKT 98                // scatter buckets: 1024 nodes each
#define EPB 4096               // edges per k_bcnt/k_bin block

typedef __bf16 bf16_t;
typedef bf16_t bf16x8 __attribute__((ext_vector_type(8)));
typedef float f32x4 __attribute__((ext_vector_type(4)));
typedef unsigned int uint;
typedef unsigned short ushort;

// ws 4-byte-slot layout:
//   [0, ND/2)            hb   (bf16 h, [NN][128])  -- pairs alias here pre-gemm
//   [ND/2, ND)           xb   (bf16 x)
//   [ND, 3ND/2)          aggb (bf16 S*x)
//   base3 = 3ND/2:
//   csr[64*128], cqr[64*128], bktot[128] (memset covers csr..bktot),
//   cnt[NN], bbase[128], bcur[128], colsum[128], colsumsq[128],
//   ptr0[NN], dinv[NN], srow[E], wb[4096 uints]

__device__ __forceinline__ ushort f2b(float f) {
    uint u = __builtin_bit_cast(uint, f);
    u += 0x7FFFu + ((u >> 16) & 1u);          // RNE
    return (ushort)(u >> 16);
}
__device__ __forceinline__ float b2f(uint s) {
    return __builtin_bit_cast(float, s << 16);
}

// int64 edge_index => high word of every entry is 0 (ids < 100000).
__device__ __forceinline__ int detect_i64(const int* __restrict__ ei) {
    __shared__ int sflag;
    int t = threadIdx.x;
    if (t < 64) {
        int hi = ei[2 * t + 1];
        unsigned long long b = __ballot(hi == 0);
        if (t == 0) sflag = (b == ~0ull) ? 1 : 0;
    }
    __syncthreads();
    return sflag;
}

// pack x and W to bf16 (pure streaming, no atomics)
__global__ __launch_bounds__(256) void k_pack(const float* __restrict__ x,
                                              uint* __restrict__ xb,
                                              const float* __restrict__ W,
                                              uint* __restrict__ wb) {
    int i = blockIdx.x * 256 + threadIdx.x;
    const float* src;
    uint* dst;
    int j;
    if (i < ND / 8) { src = x; dst = xb; j = i; }
    else { j = i - ND / 8; if (j >= (DD * DD) / 8) return; src = W; dst = wb; }
    const float4* s4 = (const float4*)src;
    float4 a = s4[2 * j], b = s4[2 * j + 1];
    uint4 o;
    o.x = (uint)f2b(a.x) | ((uint)f2b(a.y) << 16);
    o.y = (uint)f2b(a.z) | ((uint)f2b(a.w) << 16);
    o.z = (uint)f2b(b.x) | ((uint)f2b(b.y) << 16);
    o.w = (uint)f2b(b.z) | ((uint)f2b(b.w) << 16);
    ((uint4*)dst)[j] = o;
}

// per-block LDS histogram over buckets -> 98 global atomics per block
__global__ __launch_bounds__(256) void k_bcnt(const int* __restrict__ ei,
                                              int* __restrict__ bktot, int E) {
    int f = detect_i64(ei);
    __shared__ int hist[NBKT];
    int t = threadIdx.x;
    if (t < NBKT) hist[t] = 0;
    __syncthreads();
    int base = blockIdx.x * EPB;
    int count = min(EPB, E - base);
    for (int i = t; i < count; i += 256) {
        int e = base + i;
        int c = f ? ei[2 * (E + e)] : ei[E + e];
        atomicAdd(&hist[c >> 10], 1);
    }
    __syncthreads();
    if (t < NBKT && hist[t] > 0) atomicAdd(&bktot[t], hist[t]);
}

// scan 98 bucket totals -> bbase (exclusive), init bcur
__global__ void k_bscan(const int* __restrict__ bktot, int* __restrict__ bbase,
                        int* __restrict__ bcur, int E) {
    int t = threadIdx.x;          // 128
    __shared__ int ls[NBKT];
    if (t < NBKT) ls[t] = bktot[t];
    __syncthreads();
    if (t == 0) {
        int run = 0;
        for (int i = 0; i < NBKT; ++i) { int v = ls[i]; ls[i] = run; run += v; }
    }
    __syncthreads();
    if (t < NBKT) { bbase[t] = ls[t]; bcur[t] = ls[t]; }
    if (t == 0) bbase[NBKT] = E;
}

// partition edges into NBKT destination buckets. Each block histograms EPB
// edges in LDS, reserves one contiguous run per bucket with a single global
// atomic, then writes (row,col) pairs into its private runs.
__global__ __launch_bounds__(256) void k_bin(const int* __restrict__ ei,
                                             int* __restrict__ bcur,
                                             uint2* __restrict__ pairs, int E) {
    int f = detect_i64(ei);
    __shared__ int hist[NBKT], scur[NBKT];
    int t = threadIdx.x;
    if (t < NBKT) hist[t] = 0;
    __syncthreads();
    int base = blockIdx.x * EPB;
    int count = min(EPB, E - base);
    int rr[16], cc[16];
#pragma unroll
    for (int k = 0; k < 16; ++k) {
        int i = t + k * 256;
        if (i < count) {
            int e = base + i;
            int r, c;
            if (f) { r = ei[2 * e]; c = ei[2 * (E + e)]; }
            else   { r = ei[e];     c = ei[E + e]; }
            rr[k] = r; cc[k] = c;
            atomicAdd(&hist[c >> 10], 1);
        }
    }
    __syncthreads();
    if (t < NBKT) scur[t] = atomicAdd(&bcur[t], hist[t]);
    __syncthreads();
#pragma unroll
    for (int k = 0; k < 16; ++k) {
        int i = t + k * 256;
        if (i < count) {
            int b = cc[k] >> 10;
            int pos = atomicAdd(&scur[b], 1);
            pairs[pos] = (uint2){(uint)rr[k], (uint)cc[k]};
        }
    }
}

// one block per bucket: LDS histogram of the bucket's 1024 node counters,
// LDS scan -> ptr0/cnt/dinv (coalesced), then scatter srow with LDS atomics
// only. No per-edge global atomics anywhere.
__global__ __launch_bounds__(256) void k_cnt(const uint2* __restrict__ pairs,
                                             const int* __restrict__ bbase,
                                             int* __restrict__ ptr0,
                                             int* __restrict__ cnt,
                                             float* __restrict__ dinv,
                                             int* __restrict__ srow) {
    __shared__ int hist[1024];
    __shared__ int scur[1024];
    __shared__ int ls[256];
    int b = blockIdx.x;
    int t = threadIdx.x;
    int e0 = bbase[b], e1 = bbase[b + 1];
    int nodebase = b << 10;
#pragma unroll
    for (int i = 0; i < 4; ++i) hist[t + i * 256] = 0;
    __syncthreads();
    for (int i = e0 + t; i < e1; i += 256)
        atomicAdd(&hist[(int)pairs[i].y - nodebase], 1);
    __syncthreads();
    int c4[4];
    int lsum = 0;
#pragma unroll
    for (int i = 0; i < 4; ++i) { c4[i] = hist[t * 4 + i]; lsum += c4[i]; }
    ls[t] = lsum;
    __syncthreads();
    for (int o = 1; o < 256; o <<= 1) {
        int v = (t >= o) ? ls[t - o] : 0;
        __syncthreads();
        ls[t] += v;
        __syncthreads();
    }
    int run = ls[t] - lsum + e0;
#pragma unroll
    for (int i = 0; i < 4; ++i) {
        int idx = nodebase + t * 4 + i;
        if (idx < NN) {
            ptr0[idx] = run;
            cnt[idx] = c4[i];
            dinv[idx] = c4[i] > 0 ? rsqrtf((float)c4[i]) : 0.f;
        }
        scur[t * 4 + i] = run;
        run += c4[i];
    }
    __syncthreads();
    for (int i = e0 + t; i < e1; i += 256) {
        uint2 p = pairs[i];
        int pos = atomicAdd(&scur[(int)p.y - nodebase], 1);
        srow[pos] = (int)p.x;
    }
}

// one wave per node. Lane l loads edge s+l's (src, dinv[src]) itself, then
// broadcast via shfl; xb row loads issued 4-deep.
__global__ __launch_bounds__(256) void k_gather(const uint* __restrict__ xb,
                                                const int* __restrict__ srow,
                                                const int* __restrict__ ptr0,
                                                const int* __restrict__ cnt,
                                                const float* __restrict__ dinv,
                                                uint* __restrict__ aggb) {
    int n = blockIdx.x * 4 + (threadIdx.x >> 6);
    int lane = threadIdx.x & 63;
    int s = ptr0[n];
    int k = cnt[n];
    float dc = dinv[n];
    float ax = 0.f, ay = 0.f;
    for (int base = 0; base < k; base += 64) {
        int m = min(k - base, 64);
        int rj = 0; float wj = 0.f;
        if (lane < m) { rj = srow[s + base + lane]; wj = dinv[rj]; }
        int j = 0;
        for (; j + 4 <= m; j += 4) {
            int r0 = __shfl(rj, j);     float w0 = __shfl(wj, j);
            int r1 = __shfl(rj, j + 1); float w1 = __shfl(wj, j + 1);
            int r2 = __shfl(rj, j + 2); float w2 = __shfl(wj, j + 2);
            int r3 = __shfl(rj, j + 3); float w3 = __shfl(wj, j + 3);
            uint v0 = xb[(size_t)r0 * 64 + lane];
            uint v1 = xb[(size_t)r1 * 64 + lane];
            uint v2 = xb[(size_t)r2 * 64 + lane];
            uint v3 = xb[(size_t)r3 * 64 + lane];
            ax = fmaf(w0, b2f(v0 & 0xFFFFu), ax); ay = fmaf(w0, b2f(v0 >> 16), ay);
            ax = fmaf(w1, b2f(v1 & 0xFFFFu), ax); ay = fmaf(w1, b2f(v1 >> 16), ay);
            ax = fmaf(w2, b2f(v2 & 0xFFFFu), ax); ay = fmaf(w2, b2f(v2 >> 16), ay);
            ax = fmaf(w3, b2f(v3 & 0xFFFFu), ax); ay = fmaf(w3, b2f(v3 >> 16), ay);
        }
        for (; j < m; ++j) {
            int r = __shfl(rj, j);
            float w = __shfl(wj, j);
            uint v = xb[(size_t)r * 64 + lane];
            ax = fmaf(w, b2f(v & 0xFFFFu), ax);
            ay = fmaf(w, b2f(v >> 16), ay);
        }
    }
    aggb[(size_t)n * 64 + lane] = (uint)f2b(dc * ax) | ((uint)f2b(dc * ay) << 16);
}

// hb = aggb @ W^T via MFMA bf16 + fused column stats into replicated banks.
__global__ __launch_bounds__(256, 2) void k_gemm(const ushort* __restrict__ aggb,
                                                 const ushort* __restrict__ wb,
                                                 ushort* __restrict__ hb,
                                                 float* __restrict__ csr,
                                                 float* __restrict__ cqr) {
    __shared__ ushort sA[64 * LDA];           // 17.4 KB
    __shared__ float cp[4][128], cq[4][128];  // 4 KB
    int t = threadIdx.x;
    int wave = t >> 6, lane = t & 63;
    int quad = lane >> 4, l16 = lane & 15;
    size_t rowbase = (size_t)blockIdx.x * 64;

    bf16x8 Bf[8][4];
#pragma unroll
    for (int ct = 0; ct < 8; ++ct)
#pragma unroll
        for (int ks = 0; ks < 4; ++ks) {
            const uint4* p =
                (const uint4*)(wb + (size_t)(ct * 16 + l16) * 128 + ks * 32 + quad * 8);
            Bf[ct][ks] = __builtin_bit_cast(bf16x8, *p);
        }

    // stage A (OOB rows -> zeros so fused stats stay exact)
#pragma unroll
    for (int i = 0; i < 4; ++i) {
        int c = t + i * 256;
        int r = c >> 4, pos = c & 15;
        size_t gr = rowbase + r;
        uint4 v = {0u, 0u, 0u, 0u};
        if (gr < NN) v = *(const uint4*)(aggb + gr * 128 + pos * 8);
        *(uint4*)(sA + r * LDA + pos * 8) = v;
    }
    __syncthreads();

    bf16x8 Af[4];
#pragma unroll
    for (int ks = 0; ks < 4; ++ks)
        Af[ks] = __builtin_bit_cast(
            bf16x8, *(const uint4*)(sA + (wave * 16 + l16) * LDA + ks * 32 + quad * 8));

    f32x4 acc[8];
#pragma unroll
    for (int ct = 0; ct < 8; ++ct) {
        acc[ct] = (f32x4){0.f, 0.f, 0.f, 0.f};
#pragma unroll
        for (int ks = 0; ks < 4; ++ks)
            acc[ct] = __builtin_amdgcn_mfma_f32_16x16x32_bf16(Af[ks], Bf[ct][ks],
                                                              acc[ct], 0, 0, 0);
    }

#pragma unroll
    for (int ct = 0; ct < 8; ++ct) {
        float ss = 0.f, qq = 0.f;
#pragma unroll
        for (int r = 0; r < 4; ++r) {
            float v = acc[ct][r];
            ss += v; qq += v * v;
            size_t row = rowbase + wave * 16 + quad * 4 + r;
            if (row < NN) hb[row * 128 + ct * 16 + l16] = f2b(v);
        }
        ss += __shfl_xor(ss, 16); ss += __shfl_xor(ss, 32);
        qq += __shfl_xor(qq, 16); qq += __shfl_xor(qq, 32);
        if (quad == 0) { cp[wave][ct * 16 + l16] = ss; cq[wave][ct * 16 + l16] = qq; }
    }
    __syncthreads();
    if (t < 128) {
        int rep = (blockIdx.x & (NREP - 1)) * 128 + t;
        atomicAdd(&csr[rep], cp[0][t] + cp[1][t] + cp[2][t] + cp[3][t]);
        atomicAdd(&cqr[rep], cq[0][t] + cq[1][t] + cq[2][t] + cq[3][t]);
    }
}

// fold the 64 replicas
__global__ void k_red(const float* __restrict__ csr, const float* __restrict__ cqr,
                      float* __restrict__ colsum, float* __restrict__ colsumsq) {
    int t = threadIdx.x;          // 256
    if (t < 128) {
        float s = 0.f;
        for (int i = 0; i < NREP; ++i) s += csr[i * 128 + t];
        colsum[t] = s;
    } else {
        int c = t - 128;
        float s = 0.f;
        for (int i = 0; i < NREP; ++i) s += cqr[i * 128 + c];
        colsumsq[c] = s;
    }
}

__global__ __launch_bounds__(256) void k_final(const uint* __restrict__ hb,
                                               const uint* __restrict__ xb,
                                               const float* __restrict__ gamma,
                                               const float* __restrict__ beta,
                                               const float* __restrict__ colsum,
                                               const float* __restrict__ colsumsq,
                                               float* __restrict__ out, int out_size) {
    int gid = blockIdx.x * 256 + threadIdx.x;     // 4-col group index over ND/4
    int c4 = (gid & 31) * 4;
    uint2 hv = ((const uint2*)hb)[gid];
    uint2 xv = ((const uint2*)xb)[gid];
    float hval[4] = { b2f(hv.x & 0xFFFFu), b2f(hv.x >> 16),
                      b2f(hv.y & 0xFFFFu), b2f(hv.y >> 16) };
    float xval[4] = { b2f(xv.x & 0xFFFFu), b2f(xv.x >> 16),
                      b2f(xv.y & 0xFFFFu), b2f(xv.y >> 16) };
    const float invN = 1.0f / NN;
    float4 o;
    float res[4];
#pragma unroll
    for (int j = 0; j < 4; ++j) {
        float m = colsum[c4 + j] * invN;
        float var = colsumsq[c4 + j] * invN - m * m;
        float inv = rsqrtf(var + BN_EPS);
        float val = (hval[j] - m) * inv * gamma[c4 + j] + beta[c4 + j];
        res[j] = fmaxf(val, 0.f) + xval[j];
    }
    o.x = res[0]; o.y = res[1]; o.z = res[2]; o.w = res[3];
    ((float4*)out)[gid] = o;
    if (gid == 0 && out_size > ND) out[ND] = 0.0f;
}

extern "C" void kernel_launch(void* const* d_in, const int* in_sizes, int n_in,
                              void* d_out, int out_size, void* d_ws, size_t ws_size,
                              hipStream_t stream) {
    const float* x     = (const float*)d_in[0];
    const int*   ei    = (const int*)d_in[1];
    const float* W     = (const float*)d_in[2];
    const float* gamma = (const float*)d_in[4];
    const float* beta  = (const float*)d_in[5];
    float* ws = (float*)d_ws;
    float* out = (float*)d_out;

    uint*   hb       = (uint*)ws;
    uint*   xb       = hb + ND / 2;
    uint*   aggb     = xb + ND / 2;
    float*  csr      = (float*)(aggb + ND / 2);        // 64*128
    float*  cqr      = csr + NREP * 128;               // 64*128
    int*    bktot    = (int*)(cqr + NREP * 128);       // 128 (zeroed)
    int*    cnt      = bktot + 128;                    // NN (fully written by k_cnt)
    int*    bbase    = cnt + NN;                       // 128
    int*    bcur     = bbase + 128;                    // 128
    float*  colsum   = (float*)(bcur + 128);
    float*  colsumsq = colsum + 128;
    int*    ptr0     = (int*)(colsumsq + 128);
    float*  dinv     = (float*)(ptr0 + NN);
    int*    srow     = (int*)(dinv + NN);

    int E = in_sizes[1] / 2;
    uint* wb = (uint*)(srow + E);

    // pairs alias the hb region (dead until k_gemm writes it):
    // pairs needs 2*E slots (1.6M); hb region = 6.4M slots.
    uint2* pairs = (uint2*)hb;

    int nbc = (ND / 8 + (DD * DD) / 8 + 255) / 256;
    int nbin = (E + EPB - 1) / EPB;

    // zero stat replicas + bucket totals (contiguous: csr, cqr, bktot)
    hipMemsetAsync(csr, 0, (size_t)(2 * NREP * 128 + 128) * 4, stream);
    k_bcnt<<<nbin, 256, 0, stream>>>(ei, bktot, E);
    k_pack<<<nbc, 256, 0, stream>>>(x, xb, W, wb);
    k_bscan<<<1, 128, 0, stream>>>(bktot, bbase, bcur, E);
    k_bin<<<nbin, 256, 0, stream>>>(ei, bcur, pairs, E);
    k_cnt<<<NBKT, 256, 0, stream>>>(pairs, bbase, ptr0, cnt, dinv, srow);
    k_gather<<<NN / 4, 256, 0, stream>>>(xb, srow, ptr0, cnt, dinv, aggb);
    k_gemm<<<(NN + 63) / 64, 256, 0, stream>>>((const ushort*)aggb, (const ushort*)wb,
                                               (ushort*)hb, csr, cqr);
    k_red<<<1, 256, 0, stream>>>(csr, cqr, colsum, colsumsq);
    k_final<<<ND / (256 * 4), 256, 0, stream>>>(hb, xb, gamma, beta,
                                                colsum, colsumsq, out, out_size);
}

// Round 3
// 230.762 us; speedup vs baseline: 1.2537x; 1.0806x over previous
//
#include <hip/hip_runtime.h>
#include <cstddef>

#define NN 100000
#define DD 128
#define ND (NN * DD)
#define BN_EPS 1e-5f
#define LDA 136                // LDS A row stride in bf16 elems (272 B, 16B-aligned)
#define NREP 16                // stats-accumulator replicas
#define NBKT 98                // scatter buckets: 1024 nodes each
#define EPB 4096               // edges per bcnt/k_bin block

typedef __bf16 bf16_t;
typedef bf16_t bf16x8 __attribute__((ext_vector_type(8)));
typedef float f32x4 __attribute__((ext_vector_type(4)));
typedef unsigned int uint;
typedef unsigned short ushort;

// ws 4-byte-slot layout:
//   [0, ND/2)            hb   (bf16 h, [NN][128])  -- pairs alias here pre-gemm
//   [ND/2, ND)           xb   (bf16 x)
//   [ND, 3ND/2)          aggb region retired (fused); base3 = 3ND/2:
//   csr[16*128], cqr[16*128], bktot[128], bcur[128]  (memset zeroes all),
//   cnt[NN], ptr0[NN], dinv[NN], srow[E], wb[4096 uints]

__device__ __forceinline__ ushort f2b(float f) {
    uint u = __builtin_bit_cast(uint, f);
    u += 0x7FFFu + ((u >> 16) & 1u);          // RNE
    return (ushort)(u >> 16);
}
__device__ __forceinline__ float b2f(uint s) {
    return __builtin_bit_cast(float, s << 16);
}

// int64 edge_index => high word of every entry is 0 (ids < 100000).
__device__ __forceinline__ int detect_i64(const int* __restrict__ ei) {
    __shared__ int sflag;
    int t = threadIdx.x;
    if (t < 64) {
        int hi = ei[2 * t + 1];
        unsigned long long b = __ballot(hi == 0);
        if (t == 0) sflag = (b == ~0ull) ? 1 : 0;
    }
    __syncthreads();
    return sflag;
}

// dual-role: blocks [0, nbh) LDS-histogram cols into bucket totals;
// rest pack x and W to bf16.
__global__ __launch_bounds__(256) void k_prep(const int* __restrict__ ei,
                                              int* __restrict__ bktot, int E, int nbh,
                                              const float* __restrict__ x,
                                              uint* __restrict__ xb,
                                              const float* __restrict__ W,
                                              uint* __restrict__ wb) {
    if ((int)blockIdx.x < nbh) {
        int f = detect_i64(ei);
        __shared__ int hist[NBKT];
        int t = threadIdx.x;
        if (t < NBKT) hist[t] = 0;
        __syncthreads();
        int base = blockIdx.x * EPB;
        int count = min(EPB, E - base);
        for (int i = t; i < count; i += 256) {
            int e = base + i;
            int c = f ? ei[2 * (E + e)] : ei[E + e];
            atomicAdd(&hist[c >> 10], 1);
        }
        __syncthreads();
        if (t < NBKT && hist[t] > 0) atomicAdd(&bktot[t], hist[t]);
        return;
    }
    int i = (blockIdx.x - nbh) * 256 + threadIdx.x;
    const float* src;
    uint* dst;
    int j;
    if (i < ND / 8) { src = x; dst = xb; j = i; }
    else { j = i - ND / 8; if (j >= (DD * DD) / 8) return; src = W; dst = wb; }
    const float4* s4 = (const float4*)src;
    float4 a = s4[2 * j], b = s4[2 * j + 1];
    uint4 o;
    o.x = (uint)f2b(a.x) | ((uint)f2b(a.y) << 16);
    o.y = (uint)f2b(a.z) | ((uint)f2b(a.w) << 16);
    o.z = (uint)f2b(b.x) | ((uint)f2b(b.y) << 16);
    o.w = (uint)f2b(b.z) | ((uint)f2b(b.w) << 16);
    ((uint4*)dst)[j] = o;
}

// partition edges into NBKT destination buckets. Bucket bases computed by a
// redundant per-block LDS scan of bktot (98 ints, trivial); global bcur holds
// only the in-bucket running offset (zero-initialized by memset).
__global__ __launch_bounds__(256) void k_bin(const int* __restrict__ ei,
                                             const int* __restrict__ bktot,
                                             int* __restrict__ bcur,
                                             uint2* __restrict__ pairs, int E) {
    int f = detect_i64(ei);
    __shared__ int bb[NBKT], hist[NBKT], scur[NBKT];
    int t = threadIdx.x;
    if (t < NBKT) { bb[t] = bktot[t]; hist[t] = 0; }
    __syncthreads();
    if (t == 0) {
        int run = 0;
        for (int i = 0; i < NBKT; ++i) { int v = bb[i]; bb[i] = run; run += v; }
    }
    int base = blockIdx.x * EPB;
    int count = min(EPB, E - base);
    int rr[16], cc[16];
#pragma unroll
    for (int k = 0; k < 16; ++k) {
        int i = t + k * 256;
        if (i < count) {
            int e = base + i;
            int r, c;
            if (f) { r = ei[2 * e]; c = ei[2 * (E + e)]; }
            else   { r = ei[e];     c = ei[E + e]; }
            rr[k] = r; cc[k] = c;
            atomicAdd(&hist[c >> 10], 1);
        }
    }
    __syncthreads();   // joins t0's scan and the histogram
    if (t < NBKT) scur[t] = bb[t] + atomicAdd(&bcur[t], hist[t]);
    __syncthreads();
#pragma unroll
    for (int k = 0; k < 16; ++k) {
        int i = t + k * 256;
        if (i < count) {
            int b = cc[k] >> 10;
            int pos = atomicAdd(&scur[b], 1);
            pairs[pos] = (uint2){(uint)rr[k], (uint)cc[k]};
        }
    }
}

// one block per bucket: LDS histogram of the bucket's 1024 node counters,
// LDS scan -> ptr0/cnt/dinv (coalesced), then scatter srow with LDS atomics
// only. Bucket edge range recomputed from bktot locally.
__global__ __launch_bounds__(256) void k_cnt(const uint2* __restrict__ pairs,
                                             const int* __restrict__ bktot,
                                             int* __restrict__ ptr0,
                                             int* __restrict__ cnt,
                                             float* __restrict__ dinv,
                                             int* __restrict__ srow) {
    __shared__ int hist[1024];
    __shared__ int scur[1024];
    __shared__ int ls[256];
    __shared__ int bb[NBKT];
    __shared__ int se0, se1;
    int b = blockIdx.x;
    int t = threadIdx.x;
    if (t < NBKT) bb[t] = bktot[t];
#pragma unroll
    for (int i = 0; i < 4; ++i) hist[t + i * 256] = 0;
    __syncthreads();
    if (t == 0) {
        int run = 0;
        for (int i = 0; i < b; ++i) run += bb[i];
        se0 = run; se1 = run + bb[b];
    }
    __syncthreads();
    int e0 = se0, e1 = se1;
    int nodebase = b << 10;
    for (int i = e0 + t; i < e1; i += 256)
        atomicAdd(&hist[(int)pairs[i].y - nodebase], 1);
    __syncthreads();
    int c4[4];
    int lsum = 0;
#pragma unroll
    for (int i = 0; i < 4; ++i) { c4[i] = hist[t * 4 + i]; lsum += c4[i]; }
    ls[t] = lsum;
    __syncthreads();
    for (int o = 1; o < 256; o <<= 1) {
        int v = (t >= o) ? ls[t - o] : 0;
        __syncthreads();
        ls[t] += v;
        __syncthreads();
    }
    int run = ls[t] - lsum + e0;
#pragma unroll
    for (int i = 0; i < 4; ++i) {
        int idx = nodebase + t * 4 + i;
        if (idx < NN) {
            ptr0[idx] = run;
            cnt[idx] = c4[i];
            dinv[idx] = c4[i] > 0 ? rsqrtf((float)c4[i]) : 0.f;
        }
        scur[t * 4 + i] = run;
        run += c4[i];
    }
    __syncthreads();
    for (int i = e0 + t; i < e1; i += 256) {
        uint2 p = pairs[i];
        int pos = atomicAdd(&scur[(int)p.y - nodebase], 1);
        srow[pos] = (int)p.x;
    }
}

// FUSED gather + GEMM + stats. Block = 4 waves = 64 nodes.
// Phase 1: each wave gathers 16 node rows (8-deep MLP) straight into the
// LDS A-tile. Phase 2: MFMA vs W^T with per-ct B loads (low VGPR), fused
// column-stat reduction, bf16 hb write.
__global__ __launch_bounds__(256, 4) void k_gg(const uint* __restrict__ xb,
                                               const int* __restrict__ srow,
                                               const int* __restrict__ ptr0,
                                               const int* __restrict__ cnt,
                                               const float* __restrict__ dinv,
                                               const ushort* __restrict__ wb,
                                               ushort* __restrict__ hb,
                                               float* __restrict__ csr,
                                               float* __restrict__ cqr) {
    __shared__ ushort sA[64 * LDA];           // 17.4 KB
    __shared__ float cp[4][128], cq[4][128];  // 4 KB
    int t = threadIdx.x;
    int wave = t >> 6, lane = t & 63;
    size_t rowbase = (size_t)blockIdx.x * 64;

    // --- gather phase: wave handles rows wave*16 .. wave*16+15 ---
    int mn = (int)rowbase + wave * 16 + (lane & 15);
    int sv = 0, kv = 0;
    float dv = 0.f;
    if (lane < 16 && mn < NN) { sv = ptr0[mn]; kv = cnt[mn]; dv = dinv[mn]; }
    for (int i = 0; i < 16; ++i) {
        int s = __shfl(sv, i);
        int k = __shfl(kv, i);
        float dc = __shfl(dv, i);
        float ax = 0.f, ay = 0.f;
        for (int base = 0; base < k; base += 64) {
            int m = min(k - base, 64);
            int rj = 0; float wj = 0.f;
            if (lane < m) { rj = srow[s + base + lane]; wj = dinv[rj]; }
            int j = 0;
            for (; j + 8 <= m; j += 8) {
                int r0 = __shfl(rj, j);     float w0 = __shfl(wj, j);
                int r1 = __shfl(rj, j + 1); float w1 = __shfl(wj, j + 1);
                int r2 = __shfl(rj, j + 2); float w2 = __shfl(wj, j + 2);
                int r3 = __shfl(rj, j + 3); float w3 = __shfl(wj, j + 3);
                int r4 = __shfl(rj, j + 4); float w4 = __shfl(wj, j + 4);
                int r5 = __shfl(rj, j + 5); float w5 = __shfl(wj, j + 5);
                int r6 = __shfl(rj, j + 6); float w6 = __shfl(wj, j + 6);
                int r7 = __shfl(rj, j + 7); float w7 = __shfl(wj, j + 7);
                uint v0 = xb[(size_t)r0 * 64 + lane];
                uint v1 = xb[(size_t)r1 * 64 + lane];
                uint v2 = xb[(size_t)r2 * 64 + lane];
                uint v3 = xb[(size_t)r3 * 64 + lane];
                uint v4 = xb[(size_t)r4 * 64 + lane];
                uint v5 = xb[(size_t)r5 * 64 + lane];
                uint v6 = xb[(size_t)r6 * 64 + lane];
                uint v7 = xb[(size_t)r7 * 64 + lane];
                ax = fmaf(w0, b2f(v0 & 0xFFFFu), ax); ay = fmaf(w0, b2f(v0 >> 16), ay);
                ax = fmaf(w1, b2f(v1 & 0xFFFFu), ax); ay = fmaf(w1, b2f(v1 >> 16), ay);
                ax = fmaf(w2, b2f(v2 & 0xFFFFu), ax); ay = fmaf(w2, b2f(v2 >> 16), ay);
                ax = fmaf(w3, b2f(v3 & 0xFFFFu), ax); ay = fmaf(w3, b2f(v3 >> 16), ay);
                ax = fmaf(w4, b2f(v4 & 0xFFFFu), ax); ay = fmaf(w4, b2f(v4 >> 16), ay);
                ax = fmaf(w5, b2f(v5 & 0xFFFFu), ax); ay = fmaf(w5, b2f(v5 >> 16), ay);
                ax = fmaf(w6, b2f(v6 & 0xFFFFu), ax); ay = fmaf(w6, b2f(v6 >> 16), ay);
                ax = fmaf(w7, b2f(v7 & 0xFFFFu), ax); ay = fmaf(w7, b2f(v7 >> 16), ay);
            }
            for (; j + 4 <= m; j += 4) {
                int r0 = __shfl(rj, j);     float w0 = __shfl(wj, j);
                int r1 = __shfl(rj, j + 1); float w1 = __shfl(wj, j + 1);
                int r2 = __shfl(rj, j + 2); float w2 = __shfl(wj, j + 2);
                int r3 = __shfl(rj, j + 3); float w3 = __shfl(wj, j + 3);
                uint v0 = xb[(size_t)r0 * 64 + lane];
                uint v1 = xb[(size_t)r1 * 64 + lane];
                uint v2 = xb[(size_t)r2 * 64 + lane];
                uint v3 = xb[(size_t)r3 * 64 + lane];
                ax = fmaf(w0, b2f(v0 & 0xFFFFu), ax); ay = fmaf(w0, b2f(v0 >> 16), ay);
                ax = fmaf(w1, b2f(v1 & 0xFFFFu), ax); ay = fmaf(w1, b2f(v1 >> 16), ay);
                ax = fmaf(w2, b2f(v2 & 0xFFFFu), ax); ay = fmaf(w2, b2f(v2 >> 16), ay);
                ax = fmaf(w3, b2f(v3 & 0xFFFFu), ax); ay = fmaf(w3, b2f(v3 >> 16), ay);
            }
            for (; j < m; ++j) {
                int r = __shfl(rj, j);
                float w = __shfl(wj, j);
                uint v = xb[(size_t)r * 64 + lane];
                ax = fmaf(w, b2f(v & 0xFFFFu), ax);
                ay = fmaf(w, b2f(v >> 16), ay);
            }
        }
        uint o = (uint)f2b(dc * ax) | ((uint)f2b(dc * ay) << 16);
        *(uint*)(sA + (wave * 16 + i) * LDA + lane * 2) = o;   // zeros for OOB rows
    }
    __syncthreads();

    // --- GEMM phase ---
    int quad = lane >> 4, l16 = lane & 15;
    bf16x8 Af[4];
#pragma unroll
    for (int ks = 0; ks < 4; ++ks)
        Af[ks] = __builtin_bit_cast(
            bf16x8, *(const uint4*)(sA + (wave * 16 + l16) * LDA + ks * 32 + quad * 8));

#pragma unroll
    for (int ct = 0; ct < 8; ++ct) {
        bf16x8 Bf[4];
#pragma unroll
        for (int ks = 0; ks < 4; ++ks)
            Bf[ks] = __builtin_bit_cast(
                bf16x8,
                *(const uint4*)(wb + (size_t)(ct * 16 + l16) * 128 + ks * 32 + quad * 8));
        f32x4 acc = (f32x4){0.f, 0.f, 0.f, 0.f};
#pragma unroll
        for (int ks = 0; ks < 4; ++ks)
            acc = __builtin_amdgcn_mfma_f32_16x16x32_bf16(Af[ks], Bf[ks], acc, 0, 0, 0);
        float ss = 0.f, qq = 0.f;
#pragma unroll
        for (int r = 0; r < 4; ++r) {
            float v = acc[r];
            ss += v; qq += v * v;
            size_t row = rowbase + wave * 16 + quad * 4 + r;
            if (row < NN) hb[row * 128 + ct * 16 + l16] = f2b(v);
        }
        ss += __shfl_xor(ss, 16); ss += __shfl_xor(ss, 32);
        qq += __shfl_xor(qq, 16); qq += __shfl_xor(qq, 32);
        if (quad == 0) { cp[wave][ct * 16 + l16] = ss; cq[wave][ct * 16 + l16] = qq; }
    }
    __syncthreads();
    if (t < 128) {
        int rep = (blockIdx.x & (NREP - 1)) * 128 + t;
        atomicAdd(&csr[rep], cp[0][t] + cp[1][t] + cp[2][t] + cp[3][t]);
        atomicAdd(&cqr[rep], cq[0][t] + cq[1][t] + cq[2][t] + cq[3][t]);
    }
}

// BN + relu + residual; folds the NREP stat replicas in LDS (no k_red).
// 16 elems/thread, 4096 elems (32 rows) per block.
__global__ __launch_bounds__(256) void k_final(const uint* __restrict__ hb,
                                               const uint* __restrict__ xb,
                                               const float* __restrict__ gamma,
                                               const float* __restrict__ beta,
                                               const float* __restrict__ csr,
                                               const float* __restrict__ cqr,
                                               float* __restrict__ out, int out_size) {
    __shared__ float sa[128], sb[128];
    int t = threadIdx.x;
    const float invN = 1.0f / NN;
    if (t < 128) {
        float s = 0.f;
        for (int i = 0; i < NREP; ++i) s += csr[i * 128 + t];
        sa[t] = s * invN;                       // mean (temp)
    } else {
        int c = t - 128;
        float s = 0.f;
        for (int i = 0; i < NREP; ++i) s += cqr[i * 128 + c];
        sb[c] = s * invN;                       // E[h^2] (temp)
    }
    __syncthreads();
    if (t < 128) {
        float m = sa[t];
        float var = sb[t] - m * m;
        float inv = rsqrtf(var + BN_EPS);
        float A = inv * gamma[t];
        float B = beta[t] - m * A;
        sa[t] = A; sb[t] = B;                   // res = max(h*A+B,0)+x
    }
    __syncthreads();

    int c0 = (t & 7) * 16;
    int u8 = blockIdx.x * 512 + t * 2;          // uint4 index (8 bf16 each)
    uint4 hv0 = ((const uint4*)hb)[u8], hv1 = ((const uint4*)hb)[u8 + 1];
    uint4 xv0 = ((const uint4*)xb)[u8], xv1 = ((const uint4*)xb)[u8 + 1];
    uint hu[8] = {hv0.x, hv0.y, hv0.z, hv0.w, hv1.x, hv1.y, hv1.z, hv1.w};
    uint xu[8] = {xv0.x, xv0.y, xv0.z, xv0.w, xv1.x, xv1.y, xv1.z, xv1.w};
    float res[16];
#pragma unroll
    for (int p = 0; p < 8; ++p) {
        int c = c0 + p * 2;
        float h0 = b2f(hu[p] & 0xFFFFu), h1 = b2f(hu[p] >> 16);
        float x0 = b2f(xu[p] & 0xFFFFu), x1 = b2f(xu[p] >> 16);
        res[2 * p]     = fmaxf(fmaf(h0, sa[c],     sb[c]),     0.f) + x0;
        res[2 * p + 1] = fmaxf(fmaf(h1, sa[c + 1], sb[c + 1]), 0.f) + x1;
    }
    float4* o4 = (float4*)out;
    int ob = blockIdx.x * 1024 + t * 4;
#pragma unroll
    for (int q = 0; q < 4; ++q)
        o4[ob + q] = (float4){res[4 * q], res[4 * q + 1], res[4 * q + 2], res[4 * q + 3]};
    if (blockIdx.x == 0 && t == 0 && out_size > ND) out[ND] = 0.0f;
}

extern "C" void kernel_launch(void* const* d_in, const int* in_sizes, int n_in,
                              void* d_out, int out_size, void* d_ws, size_t ws_size,
                              hipStream_t stream) {
    const float* x     = (const float*)d_in[0];
    const int*   ei    = (const int*)d_in[1];
    const float* W     = (const float*)d_in[2];
    const float* gamma = (const float*)d_in[4];
    const float* beta  = (const float*)d_in[5];
    float* ws = (float*)d_ws;
    float* out = (float*)d_out;

    uint*   hb       = (uint*)ws;
    uint*   xb       = hb + ND / 2;
    float*  csr      = (float*)(xb + ND / 2);          // 16*128
    float*  cqr      = csr + NREP * 128;               // 16*128
    int*    bktot    = (int*)(cqr + NREP * 128);       // 128 (zeroed)
    int*    bcur     = bktot + 128;                    // 128 (zeroed)
    int*    cnt      = bcur + 128;                     // NN
    int*    ptr0     = cnt + NN;                       // NN
    float*  dinv     = (float*)(ptr0 + NN);            // NN
    int*    srow     = (int*)(dinv + NN);              // E

    int E = in_sizes[1] / 2;
    uint* wb = (uint*)(srow + E);

    // pairs alias the hb region (dead until k_gg writes it):
    // pairs needs 2*E slots (1.6M); hb region = 6.4M slots.
    uint2* pairs = (uint2*)hb;

    int nbc = (ND / 8 + (DD * DD) / 8 + 255) / 256;
    int nbin = (E + EPB - 1) / EPB;

    // zero stat replicas + bucket totals + bucket cursors (contiguous)
    hipMemsetAsync(csr, 0, (size_t)(2 * NREP * 128 + 256) * 4, stream);
    k_prep<<<nbin + nbc, 256, 0, stream>>>(ei, bktot, E, nbin, x, xb, W, wb);
    k_bin<<<nbin, 256, 0, stream>>>(ei, bktot, bcur, pairs, E);
    k_cnt<<<NBKT, 256, 0, stream>>>(pairs, bktot, ptr0, cnt, dinv, srow);
    k_gg<<<(NN + 63) / 64, 256, 0, stream>>>(xb, srow, ptr0, cnt, dinv,
                                             (const ushort*)wb, (ushort*)hb, csr, cqr);
    k_final<<<ND / 4096, 256, 0, stream>>>(hb, xb, gamma, beta, csr, cqr,
                                           out, out_size);
}